// Round 4
// baseline (73.433 us; speedup 1.0000x reference)
//
#include <hip/hip_runtime.h>

// SpikeLN: per-row (len 768) mean removal, variance, tiny-MLP "1/sqrt" scalar,
// scale + affine. One 64-lane wave per row; 12 f32/lane in registers.
// v4: grid-stride (2048 blocks, 8 rows/wave) for sustained full occupancy and
//     cross-row software pipelining; single-pass moments; nontemporal streams.

#define ROW_N 768   // elements per row
#define NEUR  8     // hidden neurons in distilled MLP

typedef float f32x4 __attribute__((ext_vector_type(4)));

__global__ __launch_bounds__(256) void spikeln_kernel(
    const float* __restrict__ x,
    const float* __restrict__ w1,    // [8]
    const float* __restrict__ b1,    // [8]
    const float* __restrict__ w2,    // [8]
    const float* __restrict__ b2,    // [1]
    const float* __restrict__ gamma, // [768]
    const float* __restrict__ beta,  // [768]
    float* __restrict__ out,
    int rows)
{
    const int lane     = threadIdx.x & 63;
    const int wave_gid = (blockIdx.x * blockDim.x + threadIdx.x) >> 6;
    const int n_waves  = (gridDim.x * blockDim.x) >> 6;

    // gamma/beta: loop-invariant, cached (hot in L2/L3)
    const f32x4* gv = reinterpret_cast<const f32x4*>(gamma);
    const f32x4* bv = reinterpret_cast<const f32x4*>(beta);
    const f32x4 g0 = gv[lane],       c0 = bv[lane];
    const f32x4 g1 = gv[lane + 64],  c1 = bv[lane + 64];
    const f32x4 g2 = gv[lane + 128], c2 = bv[lane + 128];

    // tiny-MLP params: loop-invariant scalars
    float W1[NEUR], B1[NEUR], W2[NEUR];
    #pragma unroll
    for (int j = 0; j < NEUR; ++j) { W1[j] = w1[j]; B1[j] = b1[j]; W2[j] = w2[j]; }
    const float B2 = b2[0];

    for (int row = wave_gid; row < rows; row += n_waves) {
        const f32x4* xv = reinterpret_cast<const f32x4*>(x + (size_t)row * ROW_N);
        f32x4 v0 = __builtin_nontemporal_load(&xv[lane]);
        f32x4 v1 = __builtin_nontemporal_load(&xv[lane + 64]);
        f32x4 v2 = __builtin_nontemporal_load(&xv[lane + 128]);

        // ---- single pass: sum and sum of squares ----
        float s  = ((v0.x + v0.y) + (v0.z + v0.w))
                 + ((v1.x + v1.y) + (v1.z + v1.w))
                 + ((v2.x + v2.y) + (v2.z + v2.w));
        float ss = ((v0.x * v0.x + v0.y * v0.y) + (v0.z * v0.z + v0.w * v0.w))
                 + ((v1.x * v1.x + v1.y * v1.y) + (v1.z * v1.z + v1.w * v1.w))
                 + ((v2.x * v2.x + v2.y * v2.y) + (v2.z * v2.z + v2.w * v2.w));
        #pragma unroll
        for (int off = 32; off > 0; off >>= 1) {
            s  += __shfl_xor(s,  off, 64);   // two independent chains,
            ss += __shfl_xor(ss, off, 64);   // interleaved
        }
        const float mean = s * (1.0f / ROW_N);
        const float var  = fmaf(-mean, mean, ss * (1.0f / ROW_N)); // E[x^2]-m^2

        // ---- distilled sqrt-inverse MLP (redundant per-lane) ----
        float rec = B2;
        #pragma unroll
        for (int j = 0; j < NEUR; ++j)
            rec += fmaxf(fmaf(var, W1[j], B1[j]), 0.0f) * W2[j];

        // ---- out = (x - mean) * rec * gamma + beta, nontemporal store ----
        f32x4* ov = reinterpret_cast<f32x4*>(out + (size_t)row * ROW_N);
        f32x4 o;

        o.x = fmaf((v0.x - mean) * rec, g0.x, c0.x);
        o.y = fmaf((v0.y - mean) * rec, g0.y, c0.y);
        o.z = fmaf((v0.z - mean) * rec, g0.z, c0.z);
        o.w = fmaf((v0.w - mean) * rec, g0.w, c0.w);
        __builtin_nontemporal_store(o, &ov[lane]);

        o.x = fmaf((v1.x - mean) * rec, g1.x, c1.x);
        o.y = fmaf((v1.y - mean) * rec, g1.y, c1.y);
        o.z = fmaf((v1.z - mean) * rec, g1.z, c1.z);
        o.w = fmaf((v1.w - mean) * rec, g1.w, c1.w);
        __builtin_nontemporal_store(o, &ov[lane + 64]);

        o.x = fmaf((v2.x - mean) * rec, g2.x, c2.x);
        o.y = fmaf((v2.y - mean) * rec, g2.y, c2.y);
        o.z = fmaf((v2.z - mean) * rec, g2.z, c2.z);
        o.w = fmaf((v2.w - mean) * rec, g2.w, c2.w);
        __builtin_nontemporal_store(o, &ov[lane + 128]);
    }
}

extern "C" void kernel_launch(void* const* d_in, const int* in_sizes, int n_in,
                              void* d_out, int out_size, void* d_ws, size_t ws_size,
                              hipStream_t stream) {
    const float* x     = (const float*)d_in[0];
    const float* w1    = (const float*)d_in[1];
    const float* b1    = (const float*)d_in[2];
    const float* w2    = (const float*)d_in[3];
    const float* b2    = (const float*)d_in[4];
    const float* gamma = (const float*)d_in[5];
    const float* beta  = (const float*)d_in[6];
    float* out = (float*)d_out;

    const int rows = in_sizes[0] / ROW_N;  // 65536
    // 2048 blocks x 4 waves = 8192 waves = 32 waves/CU sustained; 8 rows/wave.
    const int blocks = 2048;

    spikeln_kernel<<<blocks, 256, 0, stream>>>(x, w1, b1, w2, b2, gamma, beta,
                                               out, rows);
}

// Round 5
// 69.613 us; speedup vs baseline: 1.0549x; 1.0549x over previous
//
#include <hip/hip_runtime.h>

// SpikeLN: per-row (len 768) mean removal, variance, tiny-MLP "1/sqrt" scalar,
// scale + affine.
// v5: 2 rows per wave (one-shot grid, no loop) — 6 loads issued up front,
//     4 independent shfl-reduction chains interleaved, 2 MLPs interleaved.
//     Single-pass moments; nontemporal x/out streams.

#define ROW_N 768   // elements per row
#define NEUR  8     // hidden neurons in distilled MLP

typedef float f32x4 __attribute__((ext_vector_type(4)));

__device__ __forceinline__ float hsum12(const f32x4& a, const f32x4& b, const f32x4& c) {
    return ((a.x + a.y) + (a.z + a.w))
         + ((b.x + b.y) + (b.z + b.w))
         + ((c.x + c.y) + (c.z + c.w));
}
__device__ __forceinline__ float hsumsq12(const f32x4& a, const f32x4& b, const f32x4& c) {
    return ((a.x * a.x + a.y * a.y) + (a.z * a.z + a.w * a.w))
         + ((b.x * b.x + b.y * b.y) + (b.z * b.z + b.w * b.w))
         + ((c.x * c.x + c.y * c.y) + (c.z * c.z + c.w * c.w));
}

__global__ __launch_bounds__(256) void spikeln_kernel(
    const float* __restrict__ x,
    const float* __restrict__ w1,    // [8]
    const float* __restrict__ b1,    // [8]
    const float* __restrict__ w2,    // [8]
    const float* __restrict__ b2,    // [1]
    const float* __restrict__ gamma, // [768]
    const float* __restrict__ beta,  // [768]
    float* __restrict__ out,
    int rows)
{
    const int lane = threadIdx.x & 63;
    const int wid  = (blockIdx.x * blockDim.x + threadIdx.x) >> 6;
    const int rowA = wid * 2;
    const int rowB = rowA + 1;
    if (rowA >= rows) return;

    // ---- issue all 6 row loads up front (nontemporal, streamed once) ----
    const f32x4* xa = reinterpret_cast<const f32x4*>(x + (size_t)rowA * ROW_N);
    const f32x4* xb = reinterpret_cast<const f32x4*>(x + (size_t)rowB * ROW_N);
    f32x4 a0 = __builtin_nontemporal_load(&xa[lane]);
    f32x4 a1 = __builtin_nontemporal_load(&xa[lane + 64]);
    f32x4 a2 = __builtin_nontemporal_load(&xa[lane + 128]);
    f32x4 d0 = __builtin_nontemporal_load(&xb[lane]);
    f32x4 d1 = __builtin_nontemporal_load(&xb[lane + 64]);
    f32x4 d2 = __builtin_nontemporal_load(&xb[lane + 128]);

    // ---- moments: 4 independent chains through one shfl ladder ----
    float sA  = hsum12(a0, a1, a2);
    float ssA = hsumsq12(a0, a1, a2);
    float sB  = hsum12(d0, d1, d2);
    float ssB = hsumsq12(d0, d1, d2);
    #pragma unroll
    for (int off = 32; off > 0; off >>= 1) {
        sA  += __shfl_xor(sA,  off, 64);
        ssA += __shfl_xor(ssA, off, 64);
        sB  += __shfl_xor(sB,  off, 64);
        ssB += __shfl_xor(ssB, off, 64);
    }
    const float meanA = sA * (1.0f / ROW_N);
    const float meanB = sB * (1.0f / ROW_N);
    const float varA  = fmaf(-meanA, meanA, ssA * (1.0f / ROW_N));
    const float varB  = fmaf(-meanB, meanB, ssB * (1.0f / ROW_N));

    // ---- distilled sqrt-inverse MLPs (interleaved, uniform loads) ----
    float recA = b2[0], recB = recA;
    #pragma unroll
    for (int j = 0; j < NEUR; ++j) {
        const float W1 = w1[j], B1 = b1[j], W2 = w2[j];
        recA += fmaxf(fmaf(varA, W1, B1), 0.0f) * W2;
        recB += fmaxf(fmaf(varB, W1, B1), 0.0f) * W2;
    }

    // ---- out = (x - mean) * rec * gamma + beta, nontemporal stores ----
    const f32x4* gv = reinterpret_cast<const f32x4*>(gamma);
    const f32x4* bv = reinterpret_cast<const f32x4*>(beta);
    f32x4* oa = reinterpret_cast<f32x4*>(out + (size_t)rowA * ROW_N);
    f32x4* ob = reinterpret_cast<f32x4*>(out + (size_t)rowB * ROW_N);
    f32x4 g, c, o;

    g = gv[lane]; c = bv[lane];
    o.x = fmaf((a0.x - meanA) * recA, g.x, c.x);
    o.y = fmaf((a0.y - meanA) * recA, g.y, c.y);
    o.z = fmaf((a0.z - meanA) * recA, g.z, c.z);
    o.w = fmaf((a0.w - meanA) * recA, g.w, c.w);
    __builtin_nontemporal_store(o, &oa[lane]);
    o.x = fmaf((d0.x - meanB) * recB, g.x, c.x);
    o.y = fmaf((d0.y - meanB) * recB, g.y, c.y);
    o.z = fmaf((d0.z - meanB) * recB, g.z, c.z);
    o.w = fmaf((d0.w - meanB) * recB, g.w, c.w);
    __builtin_nontemporal_store(o, &ob[lane]);

    g = gv[lane + 64]; c = bv[lane + 64];
    o.x = fmaf((a1.x - meanA) * recA, g.x, c.x);
    o.y = fmaf((a1.y - meanA) * recA, g.y, c.y);
    o.z = fmaf((a1.z - meanA) * recA, g.z, c.z);
    o.w = fmaf((a1.w - meanA) * recA, g.w, c.w);
    __builtin_nontemporal_store(o, &oa[lane + 64]);
    o.x = fmaf((d1.x - meanB) * recB, g.x, c.x);
    o.y = fmaf((d1.y - meanB) * recB, g.y, c.y);
    o.z = fmaf((d1.z - meanB) * recB, g.z, c.z);
    o.w = fmaf((d1.w - meanB) * recB, g.w, c.w);
    __builtin_nontemporal_store(o, &ob[lane + 64]);

    g = gv[lane + 128]; c = bv[lane + 128];
    o.x = fmaf((a2.x - meanA) * recA, g.x, c.x);
    o.y = fmaf((a2.y - meanA) * recA, g.y, c.y);
    o.z = fmaf((a2.z - meanA) * recA, g.z, c.z);
    o.w = fmaf((a2.w - meanA) * recA, g.w, c.w);
    __builtin_nontemporal_store(o, &oa[lane + 128]);
    o.x = fmaf((d2.x - meanB) * recB, g.x, c.x);
    o.y = fmaf((d2.y - meanB) * recB, g.y, c.y);
    o.z = fmaf((d2.z - meanB) * recB, g.z, c.z);
    o.w = fmaf((d2.w - meanB) * recB, g.w, c.w);
    __builtin_nontemporal_store(o, &ob[lane + 128]);
}

extern "C" void kernel_launch(void* const* d_in, const int* in_sizes, int n_in,
                              void* d_out, int out_size, void* d_ws, size_t ws_size,
                              hipStream_t stream) {
    const float* x     = (const float*)d_in[0];
    const float* w1    = (const float*)d_in[1];
    const float* b1    = (const float*)d_in[2];
    const float* w2    = (const float*)d_in[3];
    const float* b2    = (const float*)d_in[4];
    const float* gamma = (const float*)d_in[5];
    const float* beta  = (const float*)d_in[6];
    float* out = (float*)d_out;

    const int rows = in_sizes[0] / ROW_N;           // 65536
    // 2 rows per wave, 4 waves per block -> 8 rows per block, one-shot grid
    const int blocks = (rows + 7) / 8;              // 8192
    spikeln_kernel<<<blocks, 256, 0, stream>>>(x, w1, b1, w2, b2, gamma, beta,
                                               out, rows);
}

// Round 6
// 68.436 us; speedup vs baseline: 1.0730x; 1.0172x over previous
//
#include <hip/hip_runtime.h>

// SpikeLN: per-row (len 768) mean removal, variance, tiny-MLP "1/sqrt" scalar,
// scale + affine. One 64-lane wave per row; 12 f32/lane in registers.
// v6 == v3 (best: 68.2 us, 5.9 TB/s): single-pass moments (E[x^2]-mean^2),
// nontemporal x/out streams, one-shot grid (1 row per wave).
// v4 (grid-stride) = 73.4 us and v5 (2 rows/wave) = 69.6 us both regressed:
// wave-level TLP already hides reduction latency; this is BW-bound.

#define ROW_N 768   // elements per row
#define NEUR  8     // hidden neurons in distilled MLP

typedef float f32x4 __attribute__((ext_vector_type(4)));

__global__ __launch_bounds__(256) void spikeln_kernel(
    const float* __restrict__ x,
    const float* __restrict__ w1,    // [8]
    const float* __restrict__ b1,    // [8]
    const float* __restrict__ w2,    // [8]
    const float* __restrict__ b2,    // [1]
    const float* __restrict__ gamma, // [768]
    const float* __restrict__ beta,  // [768]
    float* __restrict__ out,
    int rows)
{
    const int gid  = blockIdx.x * blockDim.x + threadIdx.x;
    const int row  = gid >> 6;
    const int lane = threadIdx.x & 63;
    if (row >= rows) return;

    const f32x4* xv = reinterpret_cast<const f32x4*>(x + (size_t)row * ROW_N);
    // streamed once — nontemporal
    f32x4 v0 = __builtin_nontemporal_load(&xv[lane]);
    f32x4 v1 = __builtin_nontemporal_load(&xv[lane + 64]);
    f32x4 v2 = __builtin_nontemporal_load(&xv[lane + 128]);

    // gamma/beta: cached (reused by every row); issue early to overlap
    const f32x4* gv = reinterpret_cast<const f32x4*>(gamma);
    const f32x4* bv = reinterpret_cast<const f32x4*>(beta);
    f32x4 g0 = gv[lane],       c0 = bv[lane];
    f32x4 g1 = gv[lane + 64],  c1 = bv[lane + 64];
    f32x4 g2 = gv[lane + 128], c2 = bv[lane + 128];

    // ---- single pass: sum and sum of squares ----
    float s  = ((v0.x + v0.y) + (v0.z + v0.w))
             + ((v1.x + v1.y) + (v1.z + v1.w))
             + ((v2.x + v2.y) + (v2.z + v2.w));
    float ss = ((v0.x * v0.x + v0.y * v0.y) + (v0.z * v0.z + v0.w * v0.w))
             + ((v1.x * v1.x + v1.y * v1.y) + (v1.z * v1.z + v1.w * v1.w))
             + ((v2.x * v2.x + v2.y * v2.y) + (v2.z * v2.z + v2.w * v2.w));
    #pragma unroll
    for (int off = 32; off > 0; off >>= 1) {
        s  += __shfl_xor(s,  off, 64);   // two independent chains,
        ss += __shfl_xor(ss, off, 64);   // interleaved
    }
    const float mean = s * (1.0f / ROW_N);
    const float var  = fmaf(-mean, mean, ss * (1.0f / ROW_N)); // E[x^2]-mean^2

    // ---- distilled sqrt-inverse MLP (redundant per-lane; uniform loads) ----
    float rec = b2[0];
    #pragma unroll
    for (int j = 0; j < NEUR; ++j)
        rec += fmaxf(fmaf(var, w1[j], b1[j]), 0.0f) * w2[j];

    // ---- out = (x - mean) * rec * gamma + beta, nontemporal store ----
    f32x4* ov = reinterpret_cast<f32x4*>(out + (size_t)row * ROW_N);
    f32x4 o;

    o.x = fmaf((v0.x - mean) * rec, g0.x, c0.x);
    o.y = fmaf((v0.y - mean) * rec, g0.y, c0.y);
    o.z = fmaf((v0.z - mean) * rec, g0.z, c0.z);
    o.w = fmaf((v0.w - mean) * rec, g0.w, c0.w);
    __builtin_nontemporal_store(o, &ov[lane]);

    o.x = fmaf((v1.x - mean) * rec, g1.x, c1.x);
    o.y = fmaf((v1.y - mean) * rec, g1.y, c1.y);
    o.z = fmaf((v1.z - mean) * rec, g1.z, c1.z);
    o.w = fmaf((v1.w - mean) * rec, g1.w, c1.w);
    __builtin_nontemporal_store(o, &ov[lane + 64]);

    o.x = fmaf((v2.x - mean) * rec, g2.x, c2.x);
    o.y = fmaf((v2.y - mean) * rec, g2.y, c2.y);
    o.z = fmaf((v2.z - mean) * rec, g2.z, c2.z);
    o.w = fmaf((v2.w - mean) * rec, g2.w, c2.w);
    __builtin_nontemporal_store(o, &ov[lane + 128]);
}

extern "C" void kernel_launch(void* const* d_in, const int* in_sizes, int n_in,
                              void* d_out, int out_size, void* d_ws, size_t ws_size,
                              hipStream_t stream) {
    const float* x     = (const float*)d_in[0];
    const float* w1    = (const float*)d_in[1];
    const float* b1    = (const float*)d_in[2];
    const float* w2    = (const float*)d_in[3];
    const float* b2    = (const float*)d_in[4];
    const float* gamma = (const float*)d_in[5];
    const float* beta  = (const float*)d_in[6];
    float* out = (float*)d_out;

    const int rows = in_sizes[0] / ROW_N;           // 65536
    const int waves_per_block = 256 / 64;           // 4 rows per block
    const int blocks = (rows + waves_per_block - 1) / waves_per_block;

    spikeln_kernel<<<blocks, 256, 0, stream>>>(x, w1, b1, w2, b2, gamma, beta,
                                               out, rows);
}